// Round 1
// baseline (282.736 us; speedup 1.0000x reference)
//
#include <hip/hip_runtime.h>
#include <math.h>

#define S_LEN 2048
#define DM 1024
#define NH 16
#define DK 64
#define BATCH 2

typedef __attribute__((ext_vector_type(8))) short bf16x8;
typedef __attribute__((ext_vector_type(4))) float f32x4;
typedef unsigned short u16;
typedef unsigned int u32;

__device__ __forceinline__ u16 f2b(float f) {
  union { float f; u32 u; } x; x.f = f;
  u32 r = x.u + 0x7FFFu + ((x.u >> 16) & 1u);
  return (u16)(r >> 16);
}

__global__ void cvt_kernel(const float* __restrict__ in, u16* __restrict__ out, int n4) {
  int idx = blockIdx.x * blockDim.x + threadIdx.x;
  int stride = gridDim.x * blockDim.x;
  for (int i = idx; i < n4; i += stride) {
    float4 v = ((const float4*)in)[i];
    ushort4 o;
    o.x = f2b(v.x); o.y = f2b(v.y); o.z = f2b(v.z); o.w = f2b(v.w);
    ((ushort4*)out)[i] = o;
  }
}

__device__ __forceinline__ void gload_lds16(const u16* g, u16* l) {
  __builtin_amdgcn_global_load_lds((const __attribute__((address_space(1))) u32*)g,
                                   (__attribute__((address_space(3))) u32*)l, 16, 0, 0);
}

// C[M,N] = A[M,K] * B[N,K]^T   (bf16 in, f32 acc, bf16 or f32 out)
template<bool OUT_BF16>
__global__ __launch_bounds__(256) void gemm_bt(
    const u16* __restrict__ A, const u16* __restrict__ B,
    void* __restrict__ Cout, int M, int N, int K)
{
  __shared__ u16 lsA[128*32];
  __shared__ u16 lsB[128*32];
  const int tid = threadIdx.x;
  const int lane = tid & 63;
  const int wid = tid >> 6;
  const int wr = wid >> 1, wc = wid & 1;
  const int m0 = blockIdx.y * 128, n0 = blockIdx.x * 128;

  f32x4 acc[4][4];
#pragma unroll
  for (int i = 0; i < 4; ++i)
#pragma unroll
    for (int j = 0; j < 4; ++j) acc[i][j] = (f32x4){0.f, 0.f, 0.f, 0.f};

  const int ntiles = K >> 5;

  // stage tile 0
#pragma unroll
  for (int i = 0; i < 2; ++i) {
    int u = tid + i * 256;
    gload_lds16(A + (size_t)(m0 + (u >> 2)) * K + (u & 3) * 8, &lsA[u * 8]);
    gload_lds16(B + (size_t)(n0 + (u >> 2)) * K + (u & 3) * 8, &lsB[u * 8]);
  }

  for (int kt = 0; kt < ntiles; ++kt) {
    __syncthreads();   // staged tile visible (vmcnt drained by compiler)
    bf16x8 af[4], bfr[4];
    const int kOff = (lane >> 4) * 8;
#pragma unroll
    for (int m = 0; m < 4; ++m)
      af[m] = *(const bf16x8*)&lsA[(wr * 64 + m * 16 + (lane & 15)) * 32 + kOff];
#pragma unroll
    for (int n = 0; n < 4; ++n)
      bfr[n] = *(const bf16x8*)&lsB[(wc * 64 + n * 16 + (lane & 15)) * 32 + kOff];
    __syncthreads();   // all reads drained; safe to overwrite
    if (kt + 1 < ntiles) {
      int k0 = (kt + 1) << 5;
#pragma unroll
      for (int i = 0; i < 2; ++i) {
        int u = tid + i * 256;
        gload_lds16(A + (size_t)(m0 + (u >> 2)) * K + k0 + (u & 3) * 8, &lsA[u * 8]);
        gload_lds16(B + (size_t)(n0 + (u >> 2)) * K + k0 + (u & 3) * 8, &lsB[u * 8]);
      }
    }
#pragma unroll
    for (int m = 0; m < 4; ++m)
#pragma unroll
      for (int n = 0; n < 4; ++n)
        acc[m][n] = __builtin_amdgcn_mfma_f32_16x16x32_bf16(af[m], bfr[n], acc[m][n], 0, 0, 0);
  }

  const int rbase = m0 + wr * 64 + ((lane >> 4) << 2);
  const int cbase = n0 + wc * 64 + (lane & 15);
#pragma unroll
  for (int m = 0; m < 4; ++m)
#pragma unroll
    for (int n = 0; n < 4; ++n)
#pragma unroll
      for (int j = 0; j < 4; ++j) {
        int r = rbase + m * 16 + j;
        int c = cbase + n * 16;
        if (OUT_BF16)
          ((u16*)Cout)[(size_t)r * N + c] = f2b(acc[m][n][j]);
        else
          ((float*)Cout)[(size_t)r * N + c] = acc[m][n][j];
      }
}

// Flash attention, causal. Q/K/V layout: [B, S, H, DK] = [B*S, 1024] bf16.
// Block = 4 waves, 64 Q rows (16 per wave). KV tiles of 64.
__global__ __launch_bounds__(256) void attn_fwd(
    const u16* __restrict__ Qp, const u16* __restrict__ Kp, const u16* __restrict__ Vp,
    u16* __restrict__ AO)
{
  __shared__ u16 lk[64 * 72];      // K tile [kv][d], pad 8 -> 16B-aligned rows, 2-way bank
  __shared__ u16 lvt[64 * 72];     // V^T tile [d][kv]
  __shared__ u16 lp[4][16 * 72];   // per-wave P tile [qrow][kv]
  const int tid = threadIdx.x;
  const int lane = tid & 63;
  const int wid = tid >> 6;
  const int bx = blockIdx.x;
  const int b = blockIdx.y >> 4;
  const int h = blockIdx.y & 15;
  const int q0 = bx * 64;
  const size_t baseBH = (size_t)b * S_LEN * DM + h * DK;

  // Q fragments (held in registers across the whole KV loop)
  bf16x8 aq[2];
  {
    int qrow = q0 + wid * 16 + (lane & 15);
    const u16* qp = Qp + baseBH + (size_t)qrow * DM + ((lane >> 4) * 8);
    aq[0] = *(const bf16x8*)qp;
    aq[1] = *(const bf16x8*)(qp + 32);
  }

  float mrow[4], lrow[4];
  f32x4 o[4];
#pragma unroll
  for (int j = 0; j < 4; ++j) { mrow[j] = -INFINITY; lrow[j] = 0.f; }
#pragma unroll
  for (int n = 0; n < 4; ++n) o[n] = (f32x4){0.f, 0.f, 0.f, 0.f};

  const int nkv = bx + 1;
  for (int t = 0; t < nkv; ++t) {
    const int kv0 = t * 64;
    __syncthreads();   // previous tile fully consumed
    // stage K tile and V^T tile
#pragma unroll
    for (int i = 0; i < 2; ++i) {
      int u = tid + i * 256;          // 512 units of 8 bf16
      int row = u >> 3, c8 = u & 7;
      const u16* gk = Kp + baseBH + (size_t)(kv0 + row) * DM + c8 * 8;
      *(uint4*)&lk[row * 72 + c8 * 8] = *(const uint4*)gk;
      const u16* gv = Vp + baseBH + (size_t)(kv0 + row) * DM + c8 * 8;
      uint4 vv = *(const uint4*)gv;
      const u16* pv = (const u16*)&vv;
#pragma unroll
      for (int e = 0; e < 8; ++e) lvt[(c8 * 8 + e) * 72 + row] = pv[e];
    }
    __syncthreads();

    const int kOff = (lane >> 4) * 8;
    // QK^T : S[16 q x 64 kv] per wave
    f32x4 s[4];
#pragma unroll
    for (int n = 0; n < 4; ++n) {
      bf16x8 bk0 = *(const bf16x8*)&lk[(n * 16 + (lane & 15)) * 72 + kOff];
      bf16x8 bk1 = *(const bf16x8*)&lk[(n * 16 + (lane & 15)) * 72 + 32 + kOff];
      f32x4 z = (f32x4){0.f, 0.f, 0.f, 0.f};
      z = __builtin_amdgcn_mfma_f32_16x16x32_bf16(aq[0], bk0, z, 0, 0, 0);
      z = __builtin_amdgcn_mfma_f32_16x16x32_bf16(aq[1], bk1, z, 0, 0, 0);
      s[n] = z;
    }

    // scale + causal mask + online softmax (rows live in 16-lane groups)
    const int qbj = q0 + wid * 16 + ((lane >> 4) << 2);
    float pm[4][4];
    float tmax[4];
#pragma unroll
    for (int j = 0; j < 4; ++j) tmax[j] = -INFINITY;
#pragma unroll
    for (int n = 0; n < 4; ++n) {
      int col = kv0 + n * 16 + (lane & 15);
#pragma unroll
      for (int j = 0; j < 4; ++j) {
        float sv = s[n][j] * 0.125f;
        sv = (col <= qbj + j) ? sv : -INFINITY;
        pm[n][j] = sv;
        tmax[j] = fmaxf(tmax[j], sv);
      }
    }
#pragma unroll
    for (int off = 1; off < 16; off <<= 1)
#pragma unroll
      for (int j = 0; j < 4; ++j)
        tmax[j] = fmaxf(tmax[j], __shfl_xor(tmax[j], off, 64));

    float rs[4];
#pragma unroll
    for (int j = 0; j < 4; ++j) {
      float mnew = fmaxf(mrow[j], tmax[j]);
      float corr = __expf(mrow[j] - mnew);   // exp(-inf)=0 on first tile
      mrow[j] = mnew;
      float r = 0.f;
#pragma unroll
      for (int n = 0; n < 4; ++n) {
        float p = __expf(pm[n][j] - mnew);   // masked -> exp(-inf)=0
        pm[n][j] = p;
        r += p;
      }
      rs[j] = r;
      lrow[j] *= corr;
#pragma unroll
      for (int n = 0; n < 4; ++n) o[n][j] *= corr;
    }
#pragma unroll
    for (int off = 1; off < 16; off <<= 1)
#pragma unroll
      for (int j = 0; j < 4; ++j)
        rs[j] += __shfl_xor(rs[j], off, 64);
#pragma unroll
    for (int j = 0; j < 4; ++j) lrow[j] += rs[j];

    // P -> LDS (re-fragment C-layout into A-layout)
    u16* lpw = lp[wid];
#pragma unroll
    for (int n = 0; n < 4; ++n)
#pragma unroll
      for (int j = 0; j < 4; ++j)
        lpw[(((lane >> 4) << 2) + j) * 72 + n * 16 + (lane & 15)] = f2b(pm[n][j]);
    __syncthreads();

    // PV: O[16 x 64] += P[16 x 64] * V[64 x 64]
    bf16x8 ap0 = *(const bf16x8*)&lpw[(lane & 15) * 72 + kOff];
    bf16x8 ap1 = *(const bf16x8*)&lpw[(lane & 15) * 72 + 32 + kOff];
#pragma unroll
    for (int n = 0; n < 4; ++n) {
      bf16x8 bv0 = *(const bf16x8*)&lvt[(n * 16 + (lane & 15)) * 72 + kOff];
      bf16x8 bv1 = *(const bf16x8*)&lvt[(n * 16 + (lane & 15)) * 72 + 32 + kOff];
      o[n] = __builtin_amdgcn_mfma_f32_16x16x32_bf16(ap0, bv0, o[n], 0, 0, 0);
      o[n] = __builtin_amdgcn_mfma_f32_16x16x32_bf16(ap1, bv1, o[n], 0, 0, 0);
    }
  }

  // normalize + store
#pragma unroll
  for (int n = 0; n < 4; ++n)
#pragma unroll
    for (int j = 0; j < 4; ++j) {
      int qrow = q0 + wid * 16 + ((lane >> 4) << 2) + j;
      float val = o[n][j] / lrow[j];
      AO[baseBH + (size_t)qrow * DM + n * 16 + (lane & 15)] = f2b(val);
    }
}

extern "C" void kernel_launch(void* const* d_in, const int* in_sizes, int n_in,
                              void* d_out, int out_size, void* d_ws, size_t ws_size,
                              hipStream_t stream) {
  const float* q  = (const float*)d_in[0];
  const float* k  = (const float*)d_in[1];
  const float* v  = (const float*)d_in[2];
  // d_in[3] = mask : deterministic causal tril, applied analytically
  const float* wq = (const float*)d_in[4];
  const float* wk = (const float*)d_in[5];
  const float* wv = (const float*)d_in[6];
  const float* wo = (const float*)d_in[7];

  const int MS = BATCH * S_LEN;          // 4096
  const size_t nIn = (size_t)MS * DM;    // 4,194,304
  const size_t nW  = (size_t)DM * DM;    // 1,048,576

  u16* ws = (u16*)d_ws;
  u16* qb  = ws; ws += nIn;
  u16* kb  = ws; ws += nIn;
  u16* vb  = ws; ws += nIn;
  u16* wqb = ws; ws += nW;
  u16* wkb = ws; ws += nW;
  u16* wvb = ws; ws += nW;
  u16* wob = ws; ws += nW;
  u16* Qp  = ws; ws += nIn;
  u16* Kp  = ws; ws += nIn;
  u16* Vp  = ws; ws += nIn;
  u16* AO  = ws; ws += nIn;

  cvt_kernel<<<1024, 256, 0, stream>>>(q,  qb,  (int)(nIn / 4));
  cvt_kernel<<<1024, 256, 0, stream>>>(k,  kb,  (int)(nIn / 4));
  cvt_kernel<<<1024, 256, 0, stream>>>(v,  vb,  (int)(nIn / 4));
  cvt_kernel<<<256,  256, 0, stream>>>(wq, wqb, (int)(nW / 4));
  cvt_kernel<<<256,  256, 0, stream>>>(wk, wkb, (int)(nW / 4));
  cvt_kernel<<<256,  256, 0, stream>>>(wv, wvb, (int)(nW / 4));
  cvt_kernel<<<256,  256, 0, stream>>>(wo, wob, (int)(nW / 4));

  dim3 gg(DM / 128, MS / 128);           // (8, 32)
  gemm_bt<true><<<gg, 256, 0, stream>>>(qb, wqb, Qp, MS, DM, DM);
  gemm_bt<true><<<gg, 256, 0, stream>>>(kb, wkb, Kp, MS, DM, DM);
  gemm_bt<true><<<gg, 256, 0, stream>>>(vb, wvb, Vp, MS, DM, DM);

  attn_fwd<<<dim3(S_LEN / 64, BATCH * NH), 256, 0, stream>>>(Qp, Kp, Vp, AO);

  gemm_bt<false><<<gg, 256, 0, stream>>>(AO, wob, d_out, MS, DM, DM);
}

// Round 2
// 167.819 us; speedup vs baseline: 1.6848x; 1.6848x over previous
//
#include <hip/hip_runtime.h>
#include <math.h>

#define S_LEN 2048
#define DM 1024
#define NH 16
#define DK 64
#define BATCH 2
#define NQ 32          // S_LEN/64 q-tiles
#define MS (BATCH*S_LEN)

typedef __attribute__((ext_vector_type(8))) short bf16x8;
typedef __attribute__((ext_vector_type(4))) float f32x4;
typedef unsigned short u16;
typedef unsigned int u32;

__device__ __forceinline__ u16 f2b(float f) {
  union { float f; u32 u; } x; x.f = f;
  u32 r = x.u + 0x7FFFu + ((x.u >> 16) & 1u);
  return (u16)(r >> 16);
}

struct CvtArgs {
  const float* src[7];
  u16* dst[7];
  int n4[7];
};

__global__ void cvt_all(CvtArgs a) {
  const int seg = blockIdx.y;
  const float* __restrict__ in = a.src[seg];
  u16* __restrict__ out = a.dst[seg];
  const int n4 = a.n4[seg];
  int idx = blockIdx.x * blockDim.x + threadIdx.x;
  int stride = gridDim.x * blockDim.x;
  for (int i = idx; i < n4; i += stride) {
    float4 v = ((const float4*)in)[i];
    ushort4 o;
    o.x = f2b(v.x); o.y = f2b(v.y); o.z = f2b(v.z); o.w = f2b(v.w);
    ((ushort4*)out)[i] = o;
  }
}

__device__ __forceinline__ void gload_lds16(const u16* g, u16* l) {
  __builtin_amdgcn_global_load_lds((const __attribute__((address_space(1))) u32*)g,
                                   (__attribute__((address_space(3))) u32*)l, 16, 0, 0);
}

// C[M,N] = A[M,K] * B[N,K]^T   (bf16 in, f32 acc, bf16 or f32 out)
template<bool OUT_BF16>
__global__ __launch_bounds__(256) void gemm_bt(
    const u16* __restrict__ A, const u16* __restrict__ B,
    void* __restrict__ Cout, int M, int N, int K)
{
  __shared__ u16 lsA[128*32];
  __shared__ u16 lsB[128*32];
  const int tid = threadIdx.x;
  const int lane = tid & 63;
  const int wid = tid >> 6;
  const int wr = wid >> 1, wc = wid & 1;
  const int m0 = blockIdx.y * 128, n0 = blockIdx.x * 128;

  f32x4 acc[4][4];
#pragma unroll
  for (int i = 0; i < 4; ++i)
#pragma unroll
    for (int j = 0; j < 4; ++j) acc[i][j] = (f32x4){0.f, 0.f, 0.f, 0.f};

  const int ntiles = K >> 5;

#pragma unroll
  for (int i = 0; i < 2; ++i) {
    int u = tid + i * 256;
    gload_lds16(A + (size_t)(m0 + (u >> 2)) * K + (u & 3) * 8, &lsA[u * 8]);
    gload_lds16(B + (size_t)(n0 + (u >> 2)) * K + (u & 3) * 8, &lsB[u * 8]);
  }

  for (int kt = 0; kt < ntiles; ++kt) {
    __syncthreads();
    bf16x8 af[4], bfr[4];
    const int kOff = (lane >> 4) * 8;
#pragma unroll
    for (int m = 0; m < 4; ++m)
      af[m] = *(const bf16x8*)&lsA[(wr * 64 + m * 16 + (lane & 15)) * 32 + kOff];
#pragma unroll
    for (int n = 0; n < 4; ++n)
      bfr[n] = *(const bf16x8*)&lsB[(wc * 64 + n * 16 + (lane & 15)) * 32 + kOff];
    __syncthreads();
    if (kt + 1 < ntiles) {
      int k0 = (kt + 1) << 5;
#pragma unroll
      for (int i = 0; i < 2; ++i) {
        int u = tid + i * 256;
        gload_lds16(A + (size_t)(m0 + (u >> 2)) * K + k0 + (u & 3) * 8, &lsA[u * 8]);
        gload_lds16(B + (size_t)(n0 + (u >> 2)) * K + k0 + (u & 3) * 8, &lsB[u * 8]);
      }
    }
#pragma unroll
    for (int m = 0; m < 4; ++m)
#pragma unroll
      for (int n = 0; n < 4; ++n)
        acc[m][n] = __builtin_amdgcn_mfma_f32_16x16x32_bf16(af[m], bfr[n], acc[m][n], 0, 0, 0);
  }

  const int rbase = m0 + wr * 64 + ((lane >> 4) << 2);
  const int cbase = n0 + wc * 64 + (lane & 15);
#pragma unroll
  for (int m = 0; m < 4; ++m)
#pragma unroll
    for (int n = 0; n < 4; ++n)
#pragma unroll
      for (int j = 0; j < 4; ++j) {
        int r = rbase + m * 16 + j;
        int c = cbase + n * 16;
        if (OUT_BF16)
          ((u16*)Cout)[(size_t)r * N + c] = f2b(acc[m][n][j]);
        else
          ((float*)Cout)[(size_t)r * N + c] = acc[m][n][j];
      }
}

// Flash attention, causal.
// Q,K layout: [B*S, DM] bf16 (token-major, head h at col h*64).
// V layout:   PRE-TRANSPOSED Vt[DM][MS]: row e=h*64+d, col token=b*2048+s.
// Block = 4 waves, handles TWO q-tiles (pj and NQ-1-pj) -> 33 kv-iters always.
__global__ __launch_bounds__(256) void attn_fwd(
    const u16* __restrict__ Qp, const u16* __restrict__ Kp, const u16* __restrict__ Vt,
    u16* __restrict__ AO)
{
  __shared__ u16 lk[64 * 72];      // K tile [kv][d]
  __shared__ u16 lvt[64 * 72];     // V^T tile [d][kv]
  __shared__ u16 lp[4][16 * 72];   // per-wave P tile [qrow][kv] (wave-private)
  const int tid = threadIdx.x;
  const int lane = tid & 63;
  const int wid = tid >> 6;
  const int pj = blockIdx.x;       // pair index 0..15
  const int b = blockIdx.y >> 4;
  const int h = blockIdx.y & 15;
  const size_t baseQK = (size_t)b * S_LEN * DM + h * DK;
  const size_t baseV  = (size_t)h * DK * MS + (size_t)b * S_LEN;  // + d*MS + s

  const int r0 = tid >> 3, c8 = tid & 7;      // staging chunk coords (chunk = tid)
  const int r1 = r0 + 32;                      // second chunk (tid+256)

  for (int seg = 0; seg < 2; ++seg) {
    const int qt = (seg == 0) ? pj : (NQ - 1 - pj);
    const int q0 = qt * 64;
    const int nkv = qt + 1;

    // Q fragments
    bf16x8 aq0, aq1;
    {
      int qrow = q0 + wid * 16 + (lane & 15);
      const u16* qp = Qp + baseQK + (size_t)qrow * DM + ((lane >> 4) * 8);
      aq0 = *(const bf16x8*)qp;
      aq1 = *(const bf16x8*)(qp + 32);
    }

    float mrow[4], lrow[4];
    f32x4 o[4];
#pragma unroll
    for (int j = 0; j < 4; ++j) { mrow[j] = -INFINITY; lrow[j] = 0.f; }
#pragma unroll
    for (int n = 0; n < 4; ++n) o[n] = (f32x4){0.f, 0.f, 0.f, 0.f};

    // prefetch tile 0 into registers
    uint4 pk0, pk1, pv0, pv1;
    pk0 = *(const uint4*)&Kp[baseQK + (size_t)r0 * DM + c8 * 8];
    pk1 = *(const uint4*)&Kp[baseQK + (size_t)r1 * DM + c8 * 8];
    pv0 = *(const uint4*)&Vt[baseV + (size_t)r0 * MS + c8 * 8];
    pv1 = *(const uint4*)&Vt[baseV + (size_t)r1 * MS + c8 * 8];

    for (int t = 0; t < nkv; ++t) {
      const int kv0 = t * 64;
      __syncthreads();                       // prev-tile reads done
      *(uint4*)&lk[r0 * 72 + c8 * 8] = pk0;
      *(uint4*)&lk[r1 * 72 + c8 * 8] = pk1;
      *(uint4*)&lvt[r0 * 72 + c8 * 8] = pv0;
      *(uint4*)&lvt[r1 * 72 + c8 * 8] = pv1;
      __syncthreads();                       // tile visible
      if (t + 1 < nkv) {
        const int kn = kv0 + 64;
        pk0 = *(const uint4*)&Kp[baseQK + (size_t)(kn + r0) * DM + c8 * 8];
        pk1 = *(const uint4*)&Kp[baseQK + (size_t)(kn + r1) * DM + c8 * 8];
        pv0 = *(const uint4*)&Vt[baseV + (size_t)r0 * MS + kn + c8 * 8];
        pv1 = *(const uint4*)&Vt[baseV + (size_t)r1 * MS + kn + c8 * 8];
      }

      const int kOff = (lane >> 4) * 8;
      // QK^T
      f32x4 s[4];
#pragma unroll
      for (int n = 0; n < 4; ++n) {
        bf16x8 bk0 = *(const bf16x8*)&lk[(n * 16 + (lane & 15)) * 72 + kOff];
        bf16x8 bk1 = *(const bf16x8*)&lk[(n * 16 + (lane & 15)) * 72 + 32 + kOff];
        f32x4 z = (f32x4){0.f, 0.f, 0.f, 0.f};
        z = __builtin_amdgcn_mfma_f32_16x16x32_bf16(aq0, bk0, z, 0, 0, 0);
        z = __builtin_amdgcn_mfma_f32_16x16x32_bf16(aq1, bk1, z, 0, 0, 0);
        s[n] = z;
      }

      // softmax (rows in 16-lane groups); mask only on the diagonal tile
      const int qbj = q0 + wid * 16 + ((lane >> 4) << 2);
      const bool diag = (t == nkv - 1);
      float pm[4][4];
      float tmax[4];
#pragma unroll
      for (int j = 0; j < 4; ++j) tmax[j] = -INFINITY;
#pragma unroll
      for (int n = 0; n < 4; ++n) {
        int col = kv0 + n * 16 + (lane & 15);
#pragma unroll
        for (int j = 0; j < 4; ++j) {
          float sv = s[n][j] * 0.125f;
          if (diag) sv = (col <= qbj + j) ? sv : -INFINITY;
          pm[n][j] = sv;
          tmax[j] = fmaxf(tmax[j], sv);
        }
      }
#pragma unroll
      for (int off = 1; off < 16; off <<= 1)
#pragma unroll
        for (int j = 0; j < 4; ++j)
          tmax[j] = fmaxf(tmax[j], __shfl_xor(tmax[j], off, 64));

      float rs[4];
#pragma unroll
      for (int j = 0; j < 4; ++j) {
        float mnew = fmaxf(mrow[j], tmax[j]);
        float corr = __expf(mrow[j] - mnew);
        mrow[j] = mnew;
        float r = 0.f;
#pragma unroll
        for (int n = 0; n < 4; ++n) {
          float p = __expf(pm[n][j] - mnew);
          pm[n][j] = p;
          r += p;
        }
        rs[j] = r;
        lrow[j] *= corr;
#pragma unroll
        for (int n = 0; n < 4; ++n) o[n][j] *= corr;
      }
#pragma unroll
      for (int off = 1; off < 16; off <<= 1)
#pragma unroll
        for (int j = 0; j < 4; ++j)
          rs[j] += __shfl_xor(rs[j], off, 64);
#pragma unroll
      for (int j = 0; j < 4; ++j) lrow[j] += rs[j];

      // P -> wave-private LDS (no barrier needed)
      u16* lpw = lp[wid];
#pragma unroll
      for (int n = 0; n < 4; ++n)
#pragma unroll
        for (int j = 0; j < 4; ++j)
          lpw[(((lane >> 4) << 2) + j) * 72 + n * 16 + (lane & 15)] = f2b(pm[n][j]);

      // PV
      bf16x8 ap0 = *(const bf16x8*)&lpw[(lane & 15) * 72 + kOff];
      bf16x8 ap1 = *(const bf16x8*)&lpw[(lane & 15) * 72 + 32 + kOff];
#pragma unroll
      for (int n = 0; n < 4; ++n) {
        bf16x8 bv0 = *(const bf16x8*)&lvt[(n * 16 + (lane & 15)) * 72 + kOff];
        bf16x8 bv1 = *(const bf16x8*)&lvt[(n * 16 + (lane & 15)) * 72 + 32 + kOff];
        o[n] = __builtin_amdgcn_mfma_f32_16x16x32_bf16(ap0, bv0, o[n], 0, 0, 0);
        o[n] = __builtin_amdgcn_mfma_f32_16x16x32_bf16(ap1, bv1, o[n], 0, 0, 0);
      }
    }

    // normalize + store
#pragma unroll
    for (int n = 0; n < 4; ++n)
#pragma unroll
      for (int j = 0; j < 4; ++j) {
        int qrow = q0 + wid * 16 + ((lane >> 4) << 2) + j;
        float val = o[n][j] / lrow[j];
        AO[baseQK + (size_t)qrow * DM + n * 16 + (lane & 15)] = f2b(val);
      }
  }
}

extern "C" void kernel_launch(void* const* d_in, const int* in_sizes, int n_in,
                              void* d_out, int out_size, void* d_ws, size_t ws_size,
                              hipStream_t stream) {
  const float* q  = (const float*)d_in[0];
  const float* k  = (const float*)d_in[1];
  const float* v  = (const float*)d_in[2];
  // d_in[3] = mask : deterministic causal tril, applied analytically
  const float* wq = (const float*)d_in[4];
  const float* wk = (const float*)d_in[5];
  const float* wv = (const float*)d_in[6];
  const float* wo = (const float*)d_in[7];

  const size_t nIn = (size_t)MS * DM;
  const size_t nW  = (size_t)DM * DM;

  u16* ws = (u16*)d_ws;
  u16* qb  = ws; ws += nIn;
  u16* kb  = ws; ws += nIn;
  u16* vb  = ws; ws += nIn;
  u16* wqb = ws; ws += nW;
  u16* wkb = ws; ws += nW;
  u16* wvb = ws; ws += nW;
  u16* wob = ws; ws += nW;
  u16* Qp  = ws; ws += nIn;
  u16* Kp  = ws; ws += nIn;
  u16* Vt  = ws; ws += nIn;   // [DM][MS] transposed V projection
  u16* AO  = ws; ws += nIn;

  CvtArgs ca;
  ca.src[0] = q;  ca.dst[0] = qb;  ca.n4[0] = (int)(nIn / 4);
  ca.src[1] = k;  ca.dst[1] = kb;  ca.n4[1] = (int)(nIn / 4);
  ca.src[2] = v;  ca.dst[2] = vb;  ca.n4[2] = (int)(nIn / 4);
  ca.src[3] = wq; ca.dst[3] = wqb; ca.n4[3] = (int)(nW / 4);
  ca.src[4] = wk; ca.dst[4] = wkb; ca.n4[4] = (int)(nW / 4);
  ca.src[5] = wv; ca.dst[5] = wvb; ca.n4[5] = (int)(nW / 4);
  ca.src[6] = wo; ca.dst[6] = wob; ca.n4[6] = (int)(nW / 4);
  cvt_all<<<dim3(256, 7), 256, 0, stream>>>(ca);

  dim3 gg(DM / 128, MS / 128);           // (8, 32)
  gemm_bt<true><<<gg, 256, 0, stream>>>(qb, wqb, Qp, MS, DM, DM);
  gemm_bt<true><<<gg, 256, 0, stream>>>(kb, wkb, Kp, MS, DM, DM);
  // V^T = Wv * X^T  -> output [DM][MS], exactly the layout attention wants
  gemm_bt<true><<<dim3(MS / 128, DM / 128), 256, 0, stream>>>(wvb, vb, Vt, DM, MS, DM);

  attn_fwd<<<dim3(NQ / 2, BATCH * NH), 256, 0, stream>>>(Qp, Kp, Vt, AO);

  gemm_bt<false><<<gg, 256, 0, stream>>>(AO, wob, d_out, MS, DM, DM);
}

// Round 3
// 165.748 us; speedup vs baseline: 1.7058x; 1.0125x over previous
//
#include <hip/hip_runtime.h>
#include <math.h>

#define S_LEN 2048
#define DM 1024
#define NH 16
#define DK 64
#define BATCH 2
#define NQ 32          // S_LEN/64 q-tiles
#define MS (BATCH*S_LEN)

typedef __attribute__((ext_vector_type(8))) short bf16x8;
typedef __attribute__((ext_vector_type(4))) float f32x4;
typedef __attribute__((ext_vector_type(16))) float f32x16;
typedef unsigned short u16;
typedef unsigned int u32;

__device__ __forceinline__ u16 f2b(float f) {
  union { float f; u32 u; } x; x.f = f;
  u32 r = x.u + 0x7FFFu + ((x.u >> 16) & 1u);
  return (u16)(r >> 16);
}

__device__ __forceinline__ u32 cvtpk_bf16(float lo, float hi) {
  u32 r;
  asm volatile("v_cvt_pk_bf16_f32 %0, %1, %2" : "=v"(r) : "v"(lo), "v"(hi));
  return r;
}

struct CvtArgs {
  const float* src[7];
  u16* dst[7];
  int n4[7];
};

__global__ void cvt_all(CvtArgs a) {
  const int seg = blockIdx.y;
  const float* __restrict__ in = a.src[seg];
  u16* __restrict__ out = a.dst[seg];
  const int n4 = a.n4[seg];
  int idx = blockIdx.x * blockDim.x + threadIdx.x;
  int stride = gridDim.x * blockDim.x;
  for (int i = idx; i < n4; i += stride) {
    float4 v = ((const float4*)in)[i];
    ushort4 o;
    o.x = f2b(v.x); o.y = f2b(v.y); o.z = f2b(v.z); o.w = f2b(v.w);
    ((ushort4*)out)[i] = o;
  }
}

__device__ __forceinline__ void gload_lds16(const u16* g, u16* l) {
  __builtin_amdgcn_global_load_lds((const __attribute__((address_space(1))) u32*)g,
                                   (__attribute__((address_space(3))) u32*)l, 16, 0, 0);
}

// C[M,N] = A[M,K] * B[N,K]^T   (bf16 in, f32 acc, bf16 or f32 out)
template<bool OUT_BF16, int BM>
__global__ __launch_bounds__(256) void gemm_bt(
    const u16* __restrict__ A, const u16* __restrict__ B,
    void* __restrict__ Cout, int M, int N, int K)
{
  __shared__ u16 lsA[BM*32];
  __shared__ u16 lsB[128*32];
  constexpr int MF = BM / 32;           // M fragments per wave
  const int tid = threadIdx.x;
  const int lane = tid & 63;
  const int wid = tid >> 6;
  const int wr = wid >> 1, wc = wid & 1;
  const int m0 = blockIdx.y * BM, n0 = blockIdx.x * 128;

  f32x4 acc[MF][4];
#pragma unroll
  for (int i = 0; i < MF; ++i)
#pragma unroll
    for (int j = 0; j < 4; ++j) acc[i][j] = (f32x4){0.f, 0.f, 0.f, 0.f};

  const int ntiles = K >> 5;

#pragma unroll
  for (int i = 0; i < BM/64; ++i) {
    int u = tid + i * 256;
    gload_lds16(A + (size_t)(m0 + (u >> 2)) * K + (u & 3) * 8, &lsA[u * 8]);
  }
#pragma unroll
  for (int i = 0; i < 2; ++i) {
    int u = tid + i * 256;
    gload_lds16(B + (size_t)(n0 + (u >> 2)) * K + (u & 3) * 8, &lsB[u * 8]);
  }

  for (int kt = 0; kt < ntiles; ++kt) {
    __syncthreads();
    bf16x8 af[MF], bfr[4];
    const int kOff = (lane >> 4) * 8;
#pragma unroll
    for (int m = 0; m < MF; ++m)
      af[m] = *(const bf16x8*)&lsA[(wr * (BM/2) + m * 16 + (lane & 15)) * 32 + kOff];
#pragma unroll
    for (int n = 0; n < 4; ++n)
      bfr[n] = *(const bf16x8*)&lsB[(wc * 64 + n * 16 + (lane & 15)) * 32 + kOff];
    __syncthreads();
    if (kt + 1 < ntiles) {
      int k0 = (kt + 1) << 5;
#pragma unroll
      for (int i = 0; i < BM/64; ++i) {
        int u = tid + i * 256;
        gload_lds16(A + (size_t)(m0 + (u >> 2)) * K + k0 + (u & 3) * 8, &lsA[u * 8]);
      }
#pragma unroll
      for (int i = 0; i < 2; ++i) {
        int u = tid + i * 256;
        gload_lds16(B + (size_t)(n0 + (u >> 2)) * K + k0 + (u & 3) * 8, &lsB[u * 8]);
      }
    }
#pragma unroll
    for (int m = 0; m < MF; ++m)
#pragma unroll
      for (int n = 0; n < 4; ++n)
        acc[m][n] = __builtin_amdgcn_mfma_f32_16x16x32_bf16(af[m], bfr[n], acc[m][n], 0, 0, 0);
  }

  const int rbase = m0 + wr * (BM/2) + ((lane >> 4) << 2);
  const int cbase = n0 + wc * 64 + (lane & 15);
#pragma unroll
  for (int m = 0; m < MF; ++m)
#pragma unroll
    for (int n = 0; n < 4; ++n)
#pragma unroll
      for (int j = 0; j < 4; ++j) {
        int r = rbase + m * 16 + j;
        int c = cbase + n * 16;
        if (OUT_BF16)
          ((u16*)Cout)[(size_t)r * N + c] = f2b(acc[m][n][j]);
        else
          ((float*)Cout)[(size_t)r * N + c] = acc[m][n][j];
      }
}

// Flash attention, causal, 32x32 MFMA, swapped QK^T (T12 structure).
// Q,K: [B*S, DM] bf16 row-major. V: pre-transposed Vt[DM][MS].
// Block = 2 waves (128 thr), QBLK=64 (32 q-rows/wave), KVBLK=64.
// LPT: qt = 31 - blockIdx.x (longest first). Double-buffered swizzled LDS.
__global__ __launch_bounds__(128) void attn_fwd(
    const u16* __restrict__ Qp, const u16* __restrict__ Kp, const u16* __restrict__ Vt,
    u16* __restrict__ AO)
{
  __shared__ __align__(16) u16 lk[2][64 * 64];
  __shared__ __align__(16) u16 lvt[2][64 * 64];
  const int tid = threadIdx.x;
  const int lane = tid & 63;
  const int wid = tid >> 6;
  const int ql = lane & 31;        // q (and LDS row) sub-index
  const int h = lane >> 5;         // wave half
  const int qt = (NQ - 1) - blockIdx.x;   // LPT: long blocks first
  const int b = blockIdx.y >> 4;
  const int hh = blockIdx.y & 15;
  const int q0 = qt * 64;
  const int nkv = qt + 1;
  const size_t baseQK = (size_t)b * S_LEN * DM + hh * DK;
  const size_t baseV  = (size_t)hh * DK * MS + (size_t)b * S_LEN;

  // Q fragments (B-operand): lane holds Q[q0w+ql][d = 16ks + 8h + e]
  const int q0w = q0 + wid * 32;
  const int qg = q0w + ql;         // this lane's q row
  bf16x8 qf[4];
#pragma unroll
  for (int ks = 0; ks < 4; ++ks)
    qf[ks] = *(const bf16x8*)&Qp[baseQK + (size_t)qg * DM + ks * 16 + h * 8];

  f32x16 ot[2];
#pragma unroll
  for (int n = 0; n < 2; ++n)
#pragma unroll
    for (int r = 0; r < 16; ++r) ot[n][r] = 0.f;
  float mrun = -1e30f, lrun = 0.f;

  // stage tile 0 into buffer 0 (source pre-swizzled: LDS[row][cj] = G[row][cj^(row&7)])
#define STAGE(BUF, KV0) do { \
    _Pragma("unroll") \
    for (int j = 0; j < 4; ++j) { \
      int chunk = (wid * 4 + j) * 64 + lane; \
      int row = chunk >> 3, c8 = chunk & 7; \
      int sc = (c8 ^ (row & 7)) * 8; \
      gload_lds16(Kp + baseQK + (size_t)((KV0) + row) * DM + sc, &lk[BUF][chunk * 8]); \
    } \
    _Pragma("unroll") \
    for (int j = 0; j < 4; ++j) { \
      int chunk = (wid * 4 + j) * 64 + lane; \
      int row = chunk >> 3, c8 = chunk & 7; \
      int sc = (c8 ^ (row & 7)) * 8; \
      gload_lds16(Vt + baseV + (size_t)row * MS + (KV0) + sc, &lvt[BUF][chunk * 8]); \
    } \
  } while (0)

  STAGE(0, 0);
  int cur = 0;
  const int swz = ql & 7;

  for (int t = 0; t < nkv; ++t) {
    const int kv0 = t * 64;
    __syncthreads();                       // staged tile (and prior reads) complete
    if (t + 1 < nkv) STAGE(cur ^ 1, (kv0 + 64));

    // ---- QK^T (swapped): S^T[kv][q], col = q = ql, row = kv-local ----
    const u16* lkb = lk[cur];
    f32x16 st[2];
    __builtin_amdgcn_s_setprio(1);
#pragma unroll
    for (int c = 0; c < 2; ++c) {
#pragma unroll
      for (int r = 0; r < 16; ++r) st[c][r] = 0.f;
#pragma unroll
      for (int ks = 0; ks < 4; ++ks) {
        bf16x8 kf = *(const bf16x8*)&lkb[((c << 5) + ql) * 64 + (((2 * ks + h) ^ swz) << 3)];
        st[c] = __builtin_amdgcn_mfma_f32_32x32x16_bf16(kf, qf[ks], st[c], 0, 0, 0);
      }
    }
    __builtin_amdgcn_s_setprio(0);

    // ---- scale + causal mask (diagonal tile only) ----
    const bool diag = (t == nkv - 1);
#pragma unroll
    for (int c = 0; c < 2; ++c)
#pragma unroll
      for (int r = 0; r < 16; ++r) {
        float sv = st[c][r] * 0.125f;
        if (diag) {
          int kvg = kv0 + c * 32 + (r & 3) + 8 * (r >> 2) + 4 * h;
          sv = (kvg <= qg) ? sv : -1e30f;
        }
        st[c][r] = sv;
      }

    // ---- online softmax: per-lane scalar m/l (lane <-> q) ----
    float mt = st[0][0];
#pragma unroll
    for (int c = 0; c < 2; ++c)
#pragma unroll
      for (int r = 0; r < 16; ++r) mt = fmaxf(mt, st[c][r]);
    mt = fmaxf(mt, __int_as_float(__shfl_xor(__float_as_int(mt), 32, 64)));

    if (!__all(mt <= mrun + 8.0f)) {       // T13 defer-max
      float mnew = fmaxf(mrun, mt);
      float corr = __expf(mrun - mnew);
      lrun *= corr;
#pragma unroll
      for (int n = 0; n < 2; ++n)
#pragma unroll
        for (int r = 0; r < 16; ++r) ot[n][r] *= corr;
      mrun = mnew;
    }

    float ls = 0.f;
#pragma unroll
    for (int c = 0; c < 2; ++c)
#pragma unroll
      for (int r = 0; r < 16; ++r) {
        float p = __expf(st[c][r] - mrun);
        st[c][r] = p;
        ls += p;
      }
    ls += __int_as_float(__shfl_xor(__float_as_int(ls), 32, 64));
    lrun += ls;

    // ---- pack P to bf16 pairs ----
    u32 pk[2][8];
#pragma unroll
    for (int c = 0; c < 2; ++c)
#pragma unroll
      for (int g = 0; g < 8; ++g)
        pk[c][g] = cvtpk_bf16(st[c][2 * g], st[c][2 * g + 1]);

    // ---- PV: O^T += V^T * P, B-frag built via half-swap exchange ----
    const u16* lvb = lvt[cur];
#pragma unroll
    for (int kst = 0; kst < 4; ++kst) {
      const int c = kst >> 1, k1 = kst & 1;
      u32 w[4];
#pragma unroll
      for (int par = 0; par < 2; ++par) {
        u32 x = pk[c][4 * k1 + par];
        u32 y = pk[c][4 * k1 + 2 + par];
        u32 tt = h ? x : y;
        u32 tp = (u32)__shfl_xor((int)tt, 32, 64);
        w[par]     = h ? tp : x;   // from half 0
        w[par + 2] = h ? y : tp;   // from half 1
      }
      union { u32 u[4]; bf16x8 v; } pb;
      pb.u[0] = w[0]; pb.u[1] = w[1]; pb.u[2] = w[2]; pb.u[3] = w[3];
      __builtin_amdgcn_s_setprio(1);
#pragma unroll
      for (int n = 0; n < 2; ++n) {
        bf16x8 vf = *(const bf16x8*)&lvb[((n << 5) + ql) * 64 + (((2 * kst + h) ^ swz) << 3)];
        ot[n] = __builtin_amdgcn_mfma_f32_32x32x16_bf16(vf, pb.v, ot[n], 0, 0, 0);
      }
      __builtin_amdgcn_s_setprio(0);
    }
    cur ^= 1;
  }

  // ---- epilogue: normalize, transpose via swizzled LDS, coalesced store ----
  float linv = 1.0f / lrun;
  __syncthreads();                 // all compute done; safe to reuse lk[0]
  u16* tb = lk[0];                 // 64 q x 64 d bf16, chunk-swizzled by (q&7)
  {
    const int qL = wid * 32 + ql;
    const int xo = (qL & 7) << 4;
#pragma unroll
    for (int n = 0; n < 2; ++n)
#pragma unroll
      for (int g = 0; g < 8; ++g) {
        u32 wv = cvtpk_bf16(ot[n][2 * g] * linv, ot[n][2 * g + 1] * linv);
        int d = 32 * n + ((2 * g) & 3) + 8 * (g >> 1) + 4 * h;
        *(u32*)((char*)tb + qL * 128 + ((2 * d) ^ xo)) = wv;
      }
  }
  __syncthreads();
  {
    const int row = tid >> 1;
#pragma unroll
    for (int i = 0; i < 4; ++i) {
      int cb = (tid & 1) * 4 + i;
      uint4 val = *(const uint4*)((const char*)tb + row * 128 + 16 * (cb ^ (row & 7)));
      *(uint4*)&AO[baseQK + (size_t)(q0 + row) * DM + cb * 8] = val;
    }
  }
}

extern "C" void kernel_launch(void* const* d_in, const int* in_sizes, int n_in,
                              void* d_out, int out_size, void* d_ws, size_t ws_size,
                              hipStream_t stream) {
  const float* q  = (const float*)d_in[0];
  const float* k  = (const float*)d_in[1];
  const float* v  = (const float*)d_in[2];
  // d_in[3] = mask : deterministic causal tril, applied analytically
  const float* wq = (const float*)d_in[4];
  const float* wk = (const float*)d_in[5];
  const float* wv = (const float*)d_in[6];
  const float* wo = (const float*)d_in[7];

  const size_t nIn = (size_t)MS * DM;
  const size_t nW  = (size_t)DM * DM;

  u16* ws = (u16*)d_ws;
  u16* qb  = ws; ws += nIn;
  u16* kb  = ws; ws += nIn;
  u16* vb  = ws; ws += nIn;
  u16* wqb = ws; ws += nW;
  u16* wkb = ws; ws += nW;
  u16* wvb = ws; ws += nW;
  u16* wob = ws; ws += nW;
  u16* Qp  = ws; ws += nIn;
  u16* Kp  = ws; ws += nIn;
  u16* Vt  = ws; ws += nIn;   // [DM][MS] transposed V projection
  u16* AO  = ws; ws += nIn;

  CvtArgs ca;
  ca.src[0] = q;  ca.dst[0] = qb;  ca.n4[0] = (int)(nIn / 4);
  ca.src[1] = k;  ca.dst[1] = kb;  ca.n4[1] = (int)(nIn / 4);
  ca.src[2] = v;  ca.dst[2] = vb;  ca.n4[2] = (int)(nIn / 4);
  ca.src[3] = wq; ca.dst[3] = wqb; ca.n4[3] = (int)(nW / 4);
  ca.src[4] = wk; ca.dst[4] = wkb; ca.n4[4] = (int)(nW / 4);
  ca.src[5] = wv; ca.dst[5] = wvb; ca.n4[5] = (int)(nW / 4);
  ca.src[6] = wo; ca.dst[6] = wob; ca.n4[6] = (int)(nW / 4);
  cvt_all<<<dim3(256, 7), 256, 0, stream>>>(ca);

  gemm_bt<true,64><<<dim3(8, 64), 256, 0, stream>>>(qb, wqb, Qp, MS, DM, DM);
  gemm_bt<true,64><<<dim3(8, 64), 256, 0, stream>>>(kb, wkb, Kp, MS, DM, DM);
  // V^T = Wv * X^T  -> [DM][MS], the layout attention wants
  gemm_bt<true,64><<<dim3(32, 16), 256, 0, stream>>>(wvb, vb, Vt, DM, MS, DM);

  attn_fwd<<<dim3(NQ, BATCH * NH), 128, 0, stream>>>(Qp, Kp, Vt, AO);

  gemm_bt<false,64><<<dim3(8, 64), 256, 0, stream>>>(AO, wob, d_out, MS, DM, DM);
}